// Round 1
// baseline (109.008 us; speedup 1.0000x reference)
//
#include <hip/hip_runtime.h>
#include <math.h>

#define NK 64
#define WIDTH 512
#define HEIGHT 512

// One fused pass over the 512x512 map.
// Tiles: 64 wide x 4 high => one wave reads a contiguous 256B row segment.
// Grid = (512/64) * (512/4) = 8 * 128 = 1024 blocks of 256 threads.
__global__ __launch_bounds__(256) void focal_loss_kernel(
    const float* __restrict__ center_maps,
    const float* __restrict__ scale_maps,
    const float* __restrict__ ann,        // (B,K,4), we use batch 0 => first 256 floats
    const int*   __restrict__ stride_p,
    float* __restrict__ out)              // out[0]=center_loss, out[1]=scale_loss
{
    __shared__ int   sx1[NK], sy1[NK], sx2[NK], sy2[NK], scx[NK], scy[NK];
    __shared__ float sax[NK], say[NK], scoef[NK], slog[NK];

    const int t = threadIdx.x;
    if (t < NK) {
        const float s = (float)stride_p[0];
        const int x1 = (int)floorf(ann[t * 4 + 0] / s);
        const int y1 = (int)floorf(ann[t * 4 + 1] / s);
        const int x2 = (int)floorf(ann[t * 4 + 2] / s);
        const int y2 = (int)floorf(ann[t * 4 + 3] / s);
        const int cx = (x1 + x2) >> 1;   // values are positive
        const int cy = (y1 + y2) >> 1;
        sx1[t] = x1; sy1[t] = y1; sx2[t] = x2; sy2[t] = y2;
        scx[t] = cx; scy[t] = cy;
        sax[t] = (float)(x1 + cx);       // dist center per reference: X - x1 - cx
        say[t] = (float)(y1 + cy);
        const float R = sqrtf((float)(cx * cx + cy * cy));
        scoef[t] = -0.5f / R;
        slog[t] = logf((float)(y2 - y1)); // hgt = y2-y1 (box units), >= 8
    }
    __syncthreads();

    const int tile = blockIdx.x;
    const int x = ((tile & 7) << 6) + (t & 63);
    const int y = ((tile >> 3) << 2) + (t >> 6);
    const float xf = (float)x, yf = (float)y;
    const int p = y * WIDTH + x;

    float cm = center_maps[p];
    cm = fminf(fmaxf(cm, 1e-4f), 1.0f - 1e-4f);
    const float sm = scale_maps[p];

    float gmax = 0.0f;
    bool  pos = false;      // any in_box
    bool  is_pos = false;   // center_gt == 1
    int   best = -1;        // last-write-wins linear scatter index for scale_gt
    float sval = 0.0f;

    #pragma unroll 8
    for (int k = 0; k < NK; ++k) {
        const int dx = x - scx[k];
        const int dy = y - scy[k];
        const bool ib = (x >= sx1[k]) && (x < sx2[k]) && (y >= sy1[k]) && (y < sy2[k]);
        if (ib) {
            pos = true;
            const float fx = xf - sax[k];
            const float fy = yf - say[k];
            const float d = sqrtf(fx * fx + fy * fy);
            gmax = fmaxf(gmax, __expf(scoef[k] * d));
        }
        if (dx == dy && dx >= -2 && dx <= 2) {
            // scatter order: i*K + k with i = dx+2; later index overrides
            const int idx = (dx + 2) * NK + k;
            if (idx >= best) { best = idx; sval = slog[k]; }
            if (dx == 0) is_pos = true;   // dx==dy==0 -> box center
        }
    }

    // center loss term
    float ct;
    if (is_pos) {
        const float om = 1.0f - cm;
        ct = om * om * (-logf(cm));                       // alpha=1, (1-cm)^2 * -log(cm)
    } else if (pos) {
        float g1 = 1.0f - gmax;                           // (1-gmax)^4
        g1 = g1 * g1; g1 = g1 * g1;
        ct = g1 * cm * cm * (-logf(1.0f - cm));
    } else {
        ct = 0.0f;
    }

    // scale loss term (only where scale_gt was written; log(hgt) != 0 always)
    float st = 0.0f;
    if (best >= 0) {
        const float diff = fabsf(sval - sm);
        st = (diff <= 1.0f) ? (0.5f * diff * diff) : (diff - 0.5f);
    }

    // block reduction: wave64 shuffle, then LDS across the 4 waves
    for (int off = 32; off > 0; off >>= 1) {
        ct += __shfl_down(ct, off, 64);
        st += __shfl_down(st, off, 64);
    }
    __shared__ float wc[4], ws[4];
    const int wid = t >> 6;
    if ((t & 63) == 0) { wc[wid] = ct; ws[wid] = st; }
    __syncthreads();
    if (t == 0) {
        atomicAdd(&out[0], (wc[0] + wc[1] + wc[2] + wc[3]) * (1.0f / 64.0f));
        atomicAdd(&out[1], (ws[0] + ws[1] + ws[2] + ws[3]) * (1.0f / 64.0f));
    }
}

extern "C" void kernel_launch(void* const* d_in, const int* in_sizes, int n_in,
                              void* d_out, int out_size, void* d_ws, size_t ws_size,
                              hipStream_t stream) {
    const float* center_maps = (const float*)d_in[0];
    const float* scale_maps  = (const float*)d_in[1];
    const float* ann         = (const float*)d_in[2];
    const int*   stride_p    = (const int*)d_in[3];
    float* out = (float*)d_out;

    // d_out is poisoned to 0xAA before every launch; zero it (async memset is
    // graph-capturable).
    hipMemsetAsync(d_out, 0, 2 * sizeof(float), stream);

    focal_loss_kernel<<<1024, 256, 0, stream>>>(center_maps, scale_maps, ann,
                                                stride_p, out);
}

// Round 2
// 92.040 us; speedup vs baseline: 1.1843x; 1.1843x over previous
//
#include <hip/hip_runtime.h>
#include <math.h>

#define NK 64
#define WIDTH 512

// Fused focal-center + smooth-L1-scale loss over the (1,512,512) batch-0 map.
// Tiles: 64 wide x 4 high; grid = 8 * 128 = 1024 blocks of 256 threads.
// Key insight: pixels outside every box contribute 0 (gauss is gated by `pos`,
// scale_gt only at the 5-point diagonals), so tiles whose rect misses every
// box's influence region [x1-2, x2+1] x [y1-2, y2+1] exit without loading maps.
__global__ __launch_bounds__(256) void focal_loss_kernel(
    const float* __restrict__ center_maps,
    const float* __restrict__ scale_maps,
    const float* __restrict__ ann,        // (B,K,4), batch 0 => first 256 floats
    const int*   __restrict__ stride_p,
    float* __restrict__ out)              // out[0]=center_loss, out[1]=scale_loss
{
    __shared__ int   sx1[NK], sy1[NK], sx2[NK], sy2[NK], scx[NK], scy[NK];
    __shared__ float sax[NK], say[NK], scoef[NK], slog[NK];

    const int t = threadIdx.x;
    if (t < NK) {
        const float s = (float)stride_p[0];
        const int x1 = (int)floorf(ann[t * 4 + 0] / s);
        const int y1 = (int)floorf(ann[t * 4 + 1] / s);
        const int x2 = (int)floorf(ann[t * 4 + 2] / s);
        const int y2 = (int)floorf(ann[t * 4 + 3] / s);
        const int cx = (x1 + x2) >> 1;   // coords are positive
        const int cy = (y1 + y2) >> 1;
        sx1[t] = x1; sy1[t] = y1; sx2[t] = x2; sy2[t] = y2;
        scx[t] = cx; scy[t] = cy;
        sax[t] = (float)(x1 + cx);       // dist center per reference: X - x1 - cx
        say[t] = (float)(y1 + cy);
        const float R = sqrtf((float)(cx * cx + cy * cy));
        scoef[t] = -0.5f / R;
        slog[t] = logf((float)(y2 - y1)); // hgt >= 8, log != 0
    }
    __syncthreads();

    const int tile = blockIdx.x;
    const int tx0 = (tile & 7) << 6;
    const int ty0 = (tile >> 3) << 2;
    const int lane = t & 63;

    // Per-wave ballot: lane k tests box k's influence rect vs this tile.
    // Identical inputs across the 4 waves -> identical masks -> uniform exit.
    const int bx1 = sx1[lane], by1 = sy1[lane], bx2 = sx2[lane], by2 = sy2[lane];
    const bool ov = (bx1 - 2 <= tx0 + 63) && (bx2 + 1 >= tx0) &&
                    (by1 - 2 <= ty0 + 3)  && (by2 + 1 >= ty0);
    unsigned long long mask = __ballot(ov);
    if (mask == 0ull) return;            // ~97% of tiles: no loads, no atomics

    const int x = tx0 + lane;
    const int y = ty0 + (t >> 6);
    const float xf = (float)x, yf = (float)y;
    const int p = y * WIDTH + x;

    float cm = center_maps[p];
    cm = fminf(fmaxf(cm, 1e-4f), 1.0f - 1e-4f);
    const float sm = scale_maps[p];

    float gmax = 0.0f;
    bool  pos = false;      // any in_box
    bool  is_pos = false;   // center_gt == 1
    int   best = -1;        // last-write-wins linear scatter index
    float sval = 0.0f;

    unsigned long long m = mask;
    while (m) {
        const int k = __builtin_ctzll(m);
        m &= m - 1;
        const int dx = x - scx[k];
        const int dy = y - scy[k];
        const bool ib = (x >= sx1[k]) && (x < sx2[k]) && (y >= sy1[k]) && (y < sy2[k]);
        if (ib) {
            pos = true;
            const float fx = xf - sax[k];
            const float fy = yf - say[k];
            const float d = sqrtf(fx * fx + fy * fy);
            gmax = fmaxf(gmax, __expf(scoef[k] * d));
        }
        if (dx == dy && dx >= -2 && dx <= 2) {
            // reference scatter order: i*K + k with i = dx+2; later overrides
            const int idx = (dx + 2) * NK + k;
            if (idx >= best) { best = idx; sval = slog[k]; }
            if (dx == 0) is_pos = true;   // box center
        }
    }

    // center loss term
    float ct;
    if (is_pos) {
        const float om = 1.0f - cm;
        ct = om * om * (-logf(cm));                       // alpha=1
    } else if (pos) {
        float g1 = 1.0f - gmax;                           // (1-gmax)^4
        g1 = g1 * g1; g1 = g1 * g1;
        ct = g1 * cm * cm * (-logf(1.0f - cm));
    } else {
        ct = 0.0f;
    }

    // scale loss term (only where scale_gt written; log(hgt) never 0)
    float st = 0.0f;
    if (best >= 0) {
        const float diff = fabsf(sval - sm);
        st = (diff <= 1.0f) ? (0.5f * diff * diff) : (diff - 0.5f);
    }

    // wave64 shuffle reduction, then LDS across the 4 waves
    for (int off = 32; off > 0; off >>= 1) {
        ct += __shfl_down(ct, off, 64);
        st += __shfl_down(st, off, 64);
    }
    __shared__ float wc[4], ws[4];
    const int wid = t >> 6;
    if (lane == 0) { wc[wid] = ct; ws[wid] = st; }
    __syncthreads();
    if (t == 0) {
        atomicAdd(&out[0], (wc[0] + wc[1] + wc[2] + wc[3]) * (1.0f / 64.0f));
        atomicAdd(&out[1], (ws[0] + ws[1] + ws[2] + ws[3]) * (1.0f / 64.0f));
    }
}

extern "C" void kernel_launch(void* const* d_in, const int* in_sizes, int n_in,
                              void* d_out, int out_size, void* d_ws, size_t ws_size,
                              hipStream_t stream) {
    const float* center_maps = (const float*)d_in[0];
    const float* scale_maps  = (const float*)d_in[1];
    const float* ann         = (const float*)d_in[2];
    const int*   stride_p    = (const int*)d_in[3];
    float* out = (float*)d_out;

    // d_out is poisoned to 0xAA before every launch; zero it (async memset is
    // graph-capturable).
    hipMemsetAsync(d_out, 0, 2 * sizeof(float), stream);

    focal_loss_kernel<<<1024, 256, 0, stream>>>(center_maps, scale_maps, ann,
                                                stride_p, out);
}